// Round 12
// baseline (406.896 us; speedup 1.0000x reference)
//
#include <hip/hip_runtime.h>

#define N 8192
#define D 256
#define MAXDEG 128   // Binomial(8192,.004): mean 32.8, sd 5.7, max row ~55. 128 safe.

typedef float floatx4 __attribute__((ext_vector_type(4)));
typedef _Float16 halfx4 __attribute__((ext_vector_type(4)));

#define BM 64
#define BN 64
#define BK 16
#define GEMM_BLOCKS ((N / BM) * (D / BN))   // 512
#define SCAN_BLOCKS 2048                    // 2048 blk * 8192 vec4 = all of adj

// ---- Kernel 1 (fused): blocks [0,512) compute x = h@W (fp32 + fp16 copy);
// blocks [512, 512+2048) stream adj with a software-pipelined scan:
// each block owns a contiguous 128 KB slice, 8 batches of 4 vec4/thread,
// next batch's loads in flight while current batch is processed.
__global__ __launch_bounds__(256) void gemm_scan(const float* __restrict__ A,
                                                 const float* __restrict__ B,
                                                 float* __restrict__ C,
                                                 halfx4* __restrict__ Ch,
                                                 const float* __restrict__ adj,
                                                 unsigned* __restrict__ cnt,
                                                 int* __restrict__ idx) {
    __shared__ float As[BK][BM];
    __shared__ float Bs[BK][BN];

    const int tid = threadIdx.x;

    if (blockIdx.x < GEMM_BLOCKS) {
        const int bm = (blockIdx.x >> 2) * BM;
        const int bn = (blockIdx.x & 3) * BN;

        const int tm = (tid / 16) * 4;
        const int tn = (tid % 16) * 4;

        float acc[4][4] = {};

        const int ar = tid / 4;
        const int ak = (tid % 4) * 4;
        const int bk = tid / 16;
        const int bnn = (tid % 16) * 4;

        for (int k0 = 0; k0 < D; k0 += BK) {
            float4 av = *(const float4*)&A[(size_t)(bm + ar) * D + k0 + ak];
            float4 bv = *(const float4*)&B[(size_t)(k0 + bk) * D + bn + bnn];
            As[ak + 0][ar] = av.x;
            As[ak + 1][ar] = av.y;
            As[ak + 2][ar] = av.z;
            As[ak + 3][ar] = av.w;
            *(float4*)&Bs[bk][bnn] = bv;
            __syncthreads();
#pragma unroll
            for (int kk = 0; kk < BK; ++kk) {
                float4 a = *(const float4*)&As[kk][tm];
                float4 b = *(const float4*)&Bs[kk][tn];
                const float ae[4] = {a.x, a.y, a.z, a.w};
                const float be[4] = {b.x, b.y, b.z, b.w};
#pragma unroll
                for (int r = 0; r < 4; ++r)
#pragma unroll
                    for (int c = 0; c < 4; ++c)
                        acc[r][c] = fmaf(ae[r], be[c], acc[r][c]);
            }
            __syncthreads();
        }
#pragma unroll
        for (int r = 0; r < 4; ++r) {
            float4 o = make_float4(acc[r][0], acc[r][1], acc[r][2], acc[r][3]);
            *(float4*)&C[(size_t)(bm + tm + r) * D + bn + tn] = o;
            halfx4 oh;
            oh.x = (_Float16)o.x; oh.y = (_Float16)o.y;
            oh.z = (_Float16)o.z; oh.w = (_Float16)o.w;
            Ch[((size_t)(bm + tm + r) * D + bn + tn) / 4] = oh;
        }
    } else {
        // ---------------- software-pipelined adjacency scan ----------------
        const size_t b = blockIdx.x - GEMM_BLOCKS;   // 0..2047
        const floatx4* __restrict__ p = (const floatx4*)adj;
        size_t base = b * 8192 + tid;                // vec4 index

        floatx4 cur[4], nxt[4];
#pragma unroll
        for (int u = 0; u < 4; ++u) cur[u] = p[base + (size_t)u * 256];

#pragma unroll
        for (int r = 0; r < 8; ++r) {
            // prefetch next batch while current is processed
            if (r < 7) {
#pragma unroll
                for (int u = 0; u < 4; ++u)
                    nxt[u] = p[base + 1024 + (size_t)u * 256];
            }
#pragma unroll
            for (int u = 0; u < 4; ++u) {
                const floatx4 v = cur[u];
                if (v.x == 0.0f && v.y == 0.0f && v.z == 0.0f && v.w == 0.0f)
                    continue;
                const size_t fi = base + (size_t)u * 256;   // vec4 index
                const int i = (int)(fi >> 11);              // / (N/4)
                const int c0 = (int)(fi & 2047) * 4;
                const float ve[4] = {v.x, v.y, v.z, v.w};
#pragma unroll
                for (int t = 0; t < 4; ++t) {
                    if (ve[t] != 0.0f) {
                        const unsigned q = atomicAdd(&cnt[i], 1u);
                        if (q < MAXDEG) idx[(size_t)i * MAXDEG + q] = c0 + t;
                    }
                }
            }
#pragma unroll
            for (int u = 0; u < 4; ++u) cur[u] = nxt[u];
            base += 1024;
        }
    }
}

// ---- Kernel 2: el[i] = x[i].a_l, er[i] = x[i].a_r (fp32 x) ----------------
__global__ __launch_bounds__(256) void rowdot(const float* __restrict__ x,
                                              const float* __restrict__ a_l,
                                              const float* __restrict__ a_r,
                                              float* __restrict__ el,
                                              float* __restrict__ er) {
    const int wave = threadIdx.x >> 6;
    const int lane = threadIdx.x & 63;
    const int i = blockIdx.x * 4 + wave;

    float4 xv = *(const float4*)&x[(size_t)i * D + lane * 4];
    float4 lv = *(const float4*)&a_l[lane * 4];
    float4 rv = *(const float4*)&a_r[lane * 4];

    float dl = xv.x * lv.x + xv.y * lv.y + xv.z * lv.z + xv.w * lv.w;
    float dr = xv.x * rv.x + xv.y * rv.y + xv.z * rv.z + xv.w * rv.w;
#pragma unroll
    for (int off = 32; off > 0; off >>= 1) {
        dl += __shfl_down(dl, off, 64);
        dr += __shfl_down(dr, off, 64);
    }
    if (lane == 0) {
        el[i] = dl;
        er[i] = dr;
    }
}

// ---- Kernel 3: wave-per-row aggregate, fp16 x gather (R9 best version) ----
__global__ __launch_bounds__(256) void gat_out(const unsigned* __restrict__ cnt,
                                               const int* __restrict__ idx,
                                               const halfx4* __restrict__ xh,
                                               const float* __restrict__ el,
                                               const float* __restrict__ er,
                                               const float* __restrict__ bias,
                                               float* __restrict__ out) {
    const int wave = threadIdx.x >> 6;
    const int lane = threadIdx.x & 63;
    const int i = blockIdx.x * 4 + wave;

    const int c = min((int)cnt[i], MAXDEG);
    const float eli = el[i];

    int jv[2] = {0, 0};
    float wv[2] = {0.0f, 0.0f};
    float wsum = 0.0f;
#pragma unroll
    for (int p = 0; p < 2; ++p) {
        const int k = lane + p * 64;
        if (k < c) {
            const int j = idx[(size_t)i * MAXDEG + k];
            const float s = eli + er[j];
            const float lr = s > 0.0f ? s : 0.2f * s;
            const float w = __expf(lr);
            jv[p] = j;
            wv[p] = w;
            wsum += w;
        }
    }
#pragma unroll
    for (int off = 32; off > 0; off >>= 1) wsum += __shfl_down(wsum, off, 64);
    const float denom = fmaxf(__shfl(wsum, 0, 64), 1e-12f);

    float4 a0 = {0, 0, 0, 0}, a1 = {0, 0, 0, 0},
           a2 = {0, 0, 0, 0}, a3 = {0, 0, 0, 0};
    const int c0 = min(c, 64);
    int k = 0;
    for (; k + 4 <= c0; k += 4) {
        const int j0 = __shfl(jv[0], k + 0, 64);
        const int j1 = __shfl(jv[0], k + 1, 64);
        const int j2 = __shfl(jv[0], k + 2, 64);
        const int j3 = __shfl(jv[0], k + 3, 64);
        const float w0 = __shfl(wv[0], k + 0, 64);
        const float w1 = __shfl(wv[0], k + 1, 64);
        const float w2 = __shfl(wv[0], k + 2, 64);
        const float w3 = __shfl(wv[0], k + 3, 64);
        const halfx4 v0 = xh[(size_t)j0 * (D / 4) + lane];
        const halfx4 v1 = xh[(size_t)j1 * (D / 4) + lane];
        const halfx4 v2 = xh[(size_t)j2 * (D / 4) + lane];
        const halfx4 v3 = xh[(size_t)j3 * (D / 4) + lane];
        a0.x = fmaf(w0, (float)v0.x, a0.x); a0.y = fmaf(w0, (float)v0.y, a0.y);
        a0.z = fmaf(w0, (float)v0.z, a0.z); a0.w = fmaf(w0, (float)v0.w, a0.w);
        a1.x = fmaf(w1, (float)v1.x, a1.x); a1.y = fmaf(w1, (float)v1.y, a1.y);
        a1.z = fmaf(w1, (float)v1.z, a1.z); a1.w = fmaf(w1, (float)v1.w, a1.w);
        a2.x = fmaf(w2, (float)v2.x, a2.x); a2.y = fmaf(w2, (float)v2.y, a2.y);
        a2.z = fmaf(w2, (float)v2.z, a2.z); a2.w = fmaf(w2, (float)v2.w, a2.w);
        a3.x = fmaf(w3, (float)v3.x, a3.x); a3.y = fmaf(w3, (float)v3.y, a3.y);
        a3.z = fmaf(w3, (float)v3.z, a3.z); a3.w = fmaf(w3, (float)v3.w, a3.w);
    }
    for (; k < c0; ++k) {
        const int j = __shfl(jv[0], k, 64);
        const float w = __shfl(wv[0], k, 64);
        const halfx4 v = xh[(size_t)j * (D / 4) + lane];
        a0.x = fmaf(w, (float)v.x, a0.x); a0.y = fmaf(w, (float)v.y, a0.y);
        a0.z = fmaf(w, (float)v.z, a0.z); a0.w = fmaf(w, (float)v.w, a0.w);
    }
    for (k = 64; k < c; ++k) {  // ultra-rare (deg > 64)
        const int j = __shfl(jv[1], k - 64, 64);
        const float w = __shfl(wv[1], k - 64, 64);
        const halfx4 v = xh[(size_t)j * (D / 4) + lane];
        a0.x = fmaf(w, (float)v.x, a0.x); a0.y = fmaf(w, (float)v.y, a0.y);
        a0.z = fmaf(w, (float)v.z, a0.z); a0.w = fmaf(w, (float)v.w, a0.w);
    }

    const float inv = 1.0f / denom;
    const float4 bv = *(const float4*)&bias[lane * 4];
    float4 o;
    o.x = (a0.x + a1.x + a2.x + a3.x) * inv + bv.x;
    o.y = (a0.y + a1.y + a2.y + a3.y) * inv + bv.y;
    o.z = (a0.z + a1.z + a2.z + a3.z) * inv + bv.z;
    o.w = (a0.w + a1.w + a2.w + a3.w) * inv + bv.w;
    *(float4*)&out[(size_t)i * D + lane * 4] = o;
}

// ---------------------------------------------------------------------------
extern "C" void kernel_launch(void* const* d_in, const int* in_sizes, int n_in,
                              void* d_out, int out_size, void* d_ws, size_t ws_size,
                              hipStream_t stream) {
    const float* h = (const float*)d_in[0];
    const float* adj = (const float*)d_in[1];
    const float* weight = (const float*)d_in[2];
    const float* a_l = (const float*)d_in[3];
    const float* a_r = (const float*)d_in[4];
    const float* bias = (const float*)d_in[5];
    float* out = (float*)d_out;

    // ws: x [N*D f32] | el [N] | er [N] | cnt [N u32] | idx [N*MAXDEG int] | xh [N*D f16]
    float* x = (float*)d_ws;
    float* el = x + (size_t)N * D;
    float* er = el + N;
    unsigned* cnt = (unsigned*)(er + N);
    int* idx = (int*)(cnt + N);
    halfx4* xh = (halfx4*)(idx + (size_t)N * MAXDEG);

    (void)hipMemsetAsync(cnt, 0, N * sizeof(unsigned), stream);

    gemm_scan<<<GEMM_BLOCKS + SCAN_BLOCKS, 256, 0, stream>>>(h, weight, x, xh, adj, cnt, idx);

    rowdot<<<N / 4, 256, 0, stream>>>(x, a_l, a_r, el, er);

    gat_out<<<N / 4, 256, 0, stream>>>(cnt, idx, xh, el, er, bias, out);
}

// Round 13
// 393.565 us; speedup vs baseline: 1.0339x; 1.0339x over previous
//
#include <hip/hip_runtime.h>

#define N 8192
#define D 256
#define MAXDEG 128   // Binomial(8192,.004): mean 32.8, sd 5.7, max row ~55. 128 safe.

typedef float floatx4 __attribute__((ext_vector_type(4)));
typedef _Float16 halfx4 __attribute__((ext_vector_type(4)));

#define BM 64
#define BN 64
#define BK 16
#define GEMM_BLOCKS ((N / BM) * (D / BN))   // 512
#define SCAN_BLOCKS (N / 4)                 // 2048 blocks, 4 whole rows each

// ---- Kernel 1 (fused): blocks [0,512) compute x = h@W (fp32 + fp16 copy);
// blocks [512, 512+2048) each own 4 COMPLETE adj rows (128 KB contiguous).
// Nonzero columns compact into per-row LDS lists via LDS atomics, then one
// coalesced burst writes idx[] and a plain store writes cnt[] — zero global
// atomics in the hot loop (the candidate throttle after R4..R12 showed
// invariance to block count / ILP depth / nt hints).
__global__ __launch_bounds__(256) void gemm_scan(const float* __restrict__ A,
                                                 const float* __restrict__ B,
                                                 float* __restrict__ C,
                                                 halfx4* __restrict__ Ch,
                                                 const float* __restrict__ adj,
                                                 unsigned* __restrict__ cnt,
                                                 int* __restrict__ idx) {
    __shared__ float As[BK][BM];
    __shared__ float Bs[BK][BN];
    __shared__ int s_idx[4][MAXDEG];
    __shared__ unsigned s_cnt[4];

    const int tid = threadIdx.x;

    if (blockIdx.x < GEMM_BLOCKS) {
        const int bm = (blockIdx.x >> 2) * BM;
        const int bn = (blockIdx.x & 3) * BN;

        const int tm = (tid / 16) * 4;
        const int tn = (tid % 16) * 4;

        float acc[4][4] = {};

        const int ar = tid / 4;
        const int ak = (tid % 4) * 4;
        const int bk = tid / 16;
        const int bnn = (tid % 16) * 4;

        for (int k0 = 0; k0 < D; k0 += BK) {
            float4 av = *(const float4*)&A[(size_t)(bm + ar) * D + k0 + ak];
            float4 bv = *(const float4*)&B[(size_t)(k0 + bk) * D + bn + bnn];
            As[ak + 0][ar] = av.x;
            As[ak + 1][ar] = av.y;
            As[ak + 2][ar] = av.z;
            As[ak + 3][ar] = av.w;
            *(float4*)&Bs[bk][bnn] = bv;
            __syncthreads();
#pragma unroll
            for (int kk = 0; kk < BK; ++kk) {
                float4 a = *(const float4*)&As[kk][tm];
                float4 b = *(const float4*)&Bs[kk][tn];
                const float ae[4] = {a.x, a.y, a.z, a.w};
                const float be[4] = {b.x, b.y, b.z, b.w};
#pragma unroll
                for (int r = 0; r < 4; ++r)
#pragma unroll
                    for (int c = 0; c < 4; ++c)
                        acc[r][c] = fmaf(ae[r], be[c], acc[r][c]);
            }
            __syncthreads();
        }
#pragma unroll
        for (int r = 0; r < 4; ++r) {
            float4 o = make_float4(acc[r][0], acc[r][1], acc[r][2], acc[r][3]);
            *(float4*)&C[(size_t)(bm + tm + r) * D + bn + tn] = o;
            halfx4 oh;
            oh.x = (_Float16)o.x; oh.y = (_Float16)o.y;
            oh.z = (_Float16)o.z; oh.w = (_Float16)o.w;
            Ch[((size_t)(bm + tm + r) * D + bn + tn) / 4] = oh;
        }
    } else {
        // ------------- row-owned adjacency scan (LDS compaction) -----------
        const int b = blockIdx.x - GEMM_BLOCKS;   // 0..2047
        const int i0 = b * 4;                     // first owned row
        if (tid < 4) s_cnt[tid] = 0u;
        __syncthreads();

        const floatx4* __restrict__ p = (const floatx4*)adj;
        const size_t slab = (size_t)i0 * (N / 4); // vec4 index of slab start

#pragma unroll 1
        for (int bt = 0; bt < 8; ++bt) {
            const int lbase = bt * 1024 + tid;    // local vec4 index in slab
            floatx4 a[4];
#pragma unroll
            for (int u = 0; u < 4; ++u)
                a[u] = p[slab + lbase + u * 256];

#pragma unroll
            for (int u = 0; u < 4; ++u) {
                const floatx4 v = a[u];
                if (v.x == 0.0f && v.y == 0.0f && v.z == 0.0f && v.w == 0.0f)
                    continue;
                const int local = lbase + u * 256;        // 0..8191
                const int r = local >> 11;                // row within slab
                const int c0 = (local & 2047) * 4;        // column of v.x
                const float ve[4] = {v.x, v.y, v.z, v.w};
#pragma unroll
                for (int t = 0; t < 4; ++t) {
                    if (ve[t] != 0.0f) {
                        const unsigned q = atomicAdd(&s_cnt[r], 1u);
                        if (q < MAXDEG) s_idx[r][q] = c0 + t;
                    }
                }
            }
        }
        __syncthreads();

        // Coalesced write-out; every owned row gets cnt written (no memset).
#pragma unroll
        for (int r = 0; r < 4; ++r) {
            const int c = min((int)s_cnt[r], MAXDEG);
            for (int t = tid; t < c; t += 256)
                idx[(size_t)(i0 + r) * MAXDEG + t] = s_idx[r][t];
        }
        if (tid < 4) cnt[i0 + tid] = min(s_cnt[tid], (unsigned)MAXDEG);
    }
}

// ---- Kernel 2: el[i] = x[i].a_l, er[i] = x[i].a_r (fp32 x) ----------------
__global__ __launch_bounds__(256) void rowdot(const float* __restrict__ x,
                                              const float* __restrict__ a_l,
                                              const float* __restrict__ a_r,
                                              float* __restrict__ el,
                                              float* __restrict__ er) {
    const int wave = threadIdx.x >> 6;
    const int lane = threadIdx.x & 63;
    const int i = blockIdx.x * 4 + wave;

    float4 xv = *(const float4*)&x[(size_t)i * D + lane * 4];
    float4 lv = *(const float4*)&a_l[lane * 4];
    float4 rv = *(const float4*)&a_r[lane * 4];

    float dl = xv.x * lv.x + xv.y * lv.y + xv.z * lv.z + xv.w * lv.w;
    float dr = xv.x * rv.x + xv.y * rv.y + xv.z * rv.z + xv.w * rv.w;
#pragma unroll
    for (int off = 32; off > 0; off >>= 1) {
        dl += __shfl_down(dl, off, 64);
        dr += __shfl_down(dr, off, 64);
    }
    if (lane == 0) {
        el[i] = dl;
        er[i] = dr;
    }
}

// ---- Kernel 3: wave-per-row aggregate, fp16 x gather (R9 best version) ----
__global__ __launch_bounds__(256) void gat_out(const unsigned* __restrict__ cnt,
                                               const int* __restrict__ idx,
                                               const halfx4* __restrict__ xh,
                                               const float* __restrict__ el,
                                               const float* __restrict__ er,
                                               const float* __restrict__ bias,
                                               float* __restrict__ out) {
    const int wave = threadIdx.x >> 6;
    const int lane = threadIdx.x & 63;
    const int i = blockIdx.x * 4 + wave;

    const int c = min((int)cnt[i], MAXDEG);
    const float eli = el[i];

    int jv[2] = {0, 0};
    float wv[2] = {0.0f, 0.0f};
    float wsum = 0.0f;
#pragma unroll
    for (int p = 0; p < 2; ++p) {
        const int k = lane + p * 64;
        if (k < c) {
            const int j = idx[(size_t)i * MAXDEG + k];
            const float s = eli + er[j];
            const float lr = s > 0.0f ? s : 0.2f * s;
            const float w = __expf(lr);
            jv[p] = j;
            wv[p] = w;
            wsum += w;
        }
    }
#pragma unroll
    for (int off = 32; off > 0; off >>= 1) wsum += __shfl_down(wsum, off, 64);
    const float denom = fmaxf(__shfl(wsum, 0, 64), 1e-12f);

    float4 a0 = {0, 0, 0, 0}, a1 = {0, 0, 0, 0},
           a2 = {0, 0, 0, 0}, a3 = {0, 0, 0, 0};
    const int c0 = min(c, 64);
    int k = 0;
    for (; k + 4 <= c0; k += 4) {
        const int j0 = __shfl(jv[0], k + 0, 64);
        const int j1 = __shfl(jv[0], k + 1, 64);
        const int j2 = __shfl(jv[0], k + 2, 64);
        const int j3 = __shfl(jv[0], k + 3, 64);
        const float w0 = __shfl(wv[0], k + 0, 64);
        const float w1 = __shfl(wv[0], k + 1, 64);
        const float w2 = __shfl(wv[0], k + 2, 64);
        const float w3 = __shfl(wv[0], k + 3, 64);
        const halfx4 v0 = xh[(size_t)j0 * (D / 4) + lane];
        const halfx4 v1 = xh[(size_t)j1 * (D / 4) + lane];
        const halfx4 v2 = xh[(size_t)j2 * (D / 4) + lane];
        const halfx4 v3 = xh[(size_t)j3 * (D / 4) + lane];
        a0.x = fmaf(w0, (float)v0.x, a0.x); a0.y = fmaf(w0, (float)v0.y, a0.y);
        a0.z = fmaf(w0, (float)v0.z, a0.z); a0.w = fmaf(w0, (float)v0.w, a0.w);
        a1.x = fmaf(w1, (float)v1.x, a1.x); a1.y = fmaf(w1, (float)v1.y, a1.y);
        a1.z = fmaf(w1, (float)v1.z, a1.z); a1.w = fmaf(w1, (float)v1.w, a1.w);
        a2.x = fmaf(w2, (float)v2.x, a2.x); a2.y = fmaf(w2, (float)v2.y, a2.y);
        a2.z = fmaf(w2, (float)v2.z, a2.z); a2.w = fmaf(w2, (float)v2.w, a2.w);
        a3.x = fmaf(w3, (float)v3.x, a3.x); a3.y = fmaf(w3, (float)v3.y, a3.y);
        a3.z = fmaf(w3, (float)v3.z, a3.z); a3.w = fmaf(w3, (float)v3.w, a3.w);
    }
    for (; k < c0; ++k) {
        const int j = __shfl(jv[0], k, 64);
        const float w = __shfl(wv[0], k, 64);
        const halfx4 v = xh[(size_t)j * (D / 4) + lane];
        a0.x = fmaf(w, (float)v.x, a0.x); a0.y = fmaf(w, (float)v.y, a0.y);
        a0.z = fmaf(w, (float)v.z, a0.z); a0.w = fmaf(w, (float)v.w, a0.w);
    }
    for (k = 64; k < c; ++k) {  // ultra-rare (deg > 64)
        const int j = __shfl(jv[1], k - 64, 64);
        const float w = __shfl(wv[1], k - 64, 64);
        const halfx4 v = xh[(size_t)j * (D / 4) + lane];
        a0.x = fmaf(w, (float)v.x, a0.x); a0.y = fmaf(w, (float)v.y, a0.y);
        a0.z = fmaf(w, (float)v.z, a0.z); a0.w = fmaf(w, (float)v.w, a0.w);
    }

    const float inv = 1.0f / denom;
    const float4 bv = *(const float4*)&bias[lane * 4];
    float4 o;
    o.x = (a0.x + a1.x + a2.x + a3.x) * inv + bv.x;
    o.y = (a0.y + a1.y + a2.y + a3.y) * inv + bv.y;
    o.z = (a0.z + a1.z + a2.z + a3.z) * inv + bv.z;
    o.w = (a0.w + a1.w + a2.w + a3.w) * inv + bv.w;
    *(float4*)&out[(size_t)i * D + lane * 4] = o;
}

// ---------------------------------------------------------------------------
extern "C" void kernel_launch(void* const* d_in, const int* in_sizes, int n_in,
                              void* d_out, int out_size, void* d_ws, size_t ws_size,
                              hipStream_t stream) {
    const float* h = (const float*)d_in[0];
    const float* adj = (const float*)d_in[1];
    const float* weight = (const float*)d_in[2];
    const float* a_l = (const float*)d_in[3];
    const float* a_r = (const float*)d_in[4];
    const float* bias = (const float*)d_in[5];
    float* out = (float*)d_out;

    // ws: x [N*D f32] | el [N] | er [N] | cnt [N u32] | idx [N*MAXDEG int] | xh [N*D f16]
    float* x = (float*)d_ws;
    float* el = x + (size_t)N * D;
    float* er = el + N;
    unsigned* cnt = (unsigned*)(er + N);
    int* idx = (int*)(cnt + N);
    halfx4* xh = (halfx4*)(idx + (size_t)N * MAXDEG);

    gemm_scan<<<GEMM_BLOCKS + SCAN_BLOCKS, 256, 0, stream>>>(h, weight, x, xh, adj, cnt, idx);

    rowdot<<<N / 4, 256, 0, stream>>>(x, a_l, a_r, el, er);

    gat_out<<<N / 4, 256, 0, stream>>>(cnt, idx, xh, el, er, bias, out);
}

// Round 14
// 392.980 us; speedup vs baseline: 1.0354x; 1.0015x over previous
//
#include <hip/hip_runtime.h>

#define N 8192
#define D 256
#define MAXDEG 128   // Binomial(8192,.004): mean 32.8, sd 5.7, max row ~55. 128 safe.

typedef float floatx4 __attribute__((ext_vector_type(4)));
typedef _Float16 halfx4 __attribute__((ext_vector_type(4)));

#define BM 64
#define BN 64
#define BK 16
#define GEMM_BLOCKS ((N / BM) * (D / BN))   // 512
#define SCAN_BLOCKS (N / 4)                 // 2048 blocks, 4 whole rows each

// ---- Kernel 1 (fused):
//  blocks [0,512): x = h@W, stored fp16-only (xh); el/er col-tile partials
//    computed from the accumulator (16-lane shfl reduce, plain stores).
//  blocks [512,2560): row-owned adj scan, LDS compaction (R13 winner).
__global__ __launch_bounds__(256) void gemm_scan(const float* __restrict__ A,
                                                 const float* __restrict__ B,
                                                 halfx4* __restrict__ Ch,
                                                 const float* __restrict__ a_l,
                                                 const float* __restrict__ a_r,
                                                 float* __restrict__ el_part,
                                                 float* __restrict__ er_part,
                                                 const float* __restrict__ adj,
                                                 unsigned* __restrict__ cnt,
                                                 int* __restrict__ idx) {
    __shared__ float As[BK][BM];
    __shared__ float Bs[BK][BN];
    __shared__ int s_idx[4][MAXDEG];
    __shared__ unsigned s_cnt[4];

    const int tid = threadIdx.x;

    if (blockIdx.x < GEMM_BLOCKS) {
        const int bm = (blockIdx.x >> 2) * BM;
        const int bn = (blockIdx.x & 3) * BN;

        const int tm = (tid / 16) * 4;
        const int tn = (tid % 16) * 4;

        float acc[4][4] = {};

        const int ar = tid / 4;
        const int ak = (tid % 4) * 4;
        const int bk = tid / 16;
        const int bnn = (tid % 16) * 4;

        for (int k0 = 0; k0 < D; k0 += BK) {
            float4 av = *(const float4*)&A[(size_t)(bm + ar) * D + k0 + ak];
            float4 bv = *(const float4*)&B[(size_t)(k0 + bk) * D + bn + bnn];
            As[ak + 0][ar] = av.x;
            As[ak + 1][ar] = av.y;
            As[ak + 2][ar] = av.z;
            As[ak + 3][ar] = av.w;
            *(float4*)&Bs[bk][bnn] = bv;
            __syncthreads();
#pragma unroll
            for (int kk = 0; kk < BK; ++kk) {
                float4 a = *(const float4*)&As[kk][tm];
                float4 b = *(const float4*)&Bs[kk][tn];
                const float ae[4] = {a.x, a.y, a.z, a.w};
                const float be[4] = {b.x, b.y, b.z, b.w};
#pragma unroll
                for (int r = 0; r < 4; ++r)
#pragma unroll
                    for (int c = 0; c < 4; ++c)
                        acc[r][c] = fmaf(ae[r], be[c], acc[r][c]);
            }
            __syncthreads();
        }
        // Epilogue: fp16 x store + el/er col-tile partial dots.
        const float4 alv = *(const float4*)&a_l[bn + tn];
        const float4 arv = *(const float4*)&a_r[bn + tn];
        const int cb = bn >> 6;   // col-block 0..3
#pragma unroll
        for (int r = 0; r < 4; ++r) {
            float4 o = make_float4(acc[r][0], acc[r][1], acc[r][2], acc[r][3]);
            halfx4 oh;
            oh.x = (_Float16)o.x; oh.y = (_Float16)o.y;
            oh.z = (_Float16)o.z; oh.w = (_Float16)o.w;
            Ch[((size_t)(bm + tm + r) * D + bn + tn) / 4] = oh;

            float pl = o.x * alv.x + o.y * alv.y + o.z * alv.z + o.w * alv.w;
            float pr = o.x * arv.x + o.y * arv.y + o.z * arv.z + o.w * arv.w;
            // 16 threads (contiguous lanes) share this output row
#pragma unroll
            for (int off = 8; off > 0; off >>= 1) {
                pl += __shfl_down(pl, off, 16);
                pr += __shfl_down(pr, off, 16);
            }
            if ((tid & 15) == 0) {
                el_part[(size_t)cb * N + bm + tm + r] = pl;
                er_part[(size_t)cb * N + bm + tm + r] = pr;
            }
        }
    } else {
        // ------------- row-owned adjacency scan (LDS compaction) -----------
        const int b = blockIdx.x - GEMM_BLOCKS;   // 0..2047
        const int i0 = b * 4;                     // first owned row
        if (tid < 4) s_cnt[tid] = 0u;
        __syncthreads();

        const floatx4* __restrict__ p = (const floatx4*)adj;
        const size_t slab = (size_t)i0 * (N / 4); // vec4 index of slab start

#pragma unroll 1
        for (int bt = 0; bt < 8; ++bt) {
            const int lbase = bt * 1024 + tid;    // local vec4 index in slab
            floatx4 a[4];
#pragma unroll
            for (int u = 0; u < 4; ++u)
                a[u] = p[slab + lbase + u * 256];

#pragma unroll
            for (int u = 0; u < 4; ++u) {
                const floatx4 v = a[u];
                if (v.x == 0.0f && v.y == 0.0f && v.z == 0.0f && v.w == 0.0f)
                    continue;
                const int local = lbase + u * 256;        // 0..8191
                const int r = local >> 11;                // row within slab
                const int c0 = (local & 2047) * 4;        // column of v.x
                const float ve[4] = {v.x, v.y, v.z, v.w};
#pragma unroll
                for (int t = 0; t < 4; ++t) {
                    if (ve[t] != 0.0f) {
                        const unsigned q = atomicAdd(&s_cnt[r], 1u);
                        if (q < MAXDEG) s_idx[r][q] = c0 + t;
                    }
                }
            }
        }
        __syncthreads();

#pragma unroll
        for (int r = 0; r < 4; ++r) {
            const int c = min((int)s_cnt[r], MAXDEG);
            for (int t = tid; t < c; t += 256)
                idx[(size_t)(i0 + r) * MAXDEG + t] = s_idx[r][t];
        }
        if (tid < 4) cnt[i0 + tid] = min(s_cnt[tid], (unsigned)MAXDEG);
    }
}

// ---- Kernel 2: wave-per-row aggregate, fp16 x gather; el/er summed from
// the 4 col-tile partials in-kernel (no rowdot kernel).
__global__ __launch_bounds__(256) void gat_out(const unsigned* __restrict__ cnt,
                                               const int* __restrict__ idx,
                                               const halfx4* __restrict__ xh,
                                               const float* __restrict__ el_part,
                                               const float* __restrict__ er_part,
                                               const float* __restrict__ bias,
                                               float* __restrict__ out) {
    const int wave = threadIdx.x >> 6;
    const int lane = threadIdx.x & 63;
    const int i = blockIdx.x * 4 + wave;

    const int c = min((int)cnt[i], MAXDEG);
    // wave-uniform: 4 same-address loads -> broadcast
    const float eli = el_part[i] + el_part[N + i] + el_part[2 * N + i] +
                      el_part[3 * N + i];

    int jv[2] = {0, 0};
    float wv[2] = {0.0f, 0.0f};
    float wsum = 0.0f;
#pragma unroll
    for (int p = 0; p < 2; ++p) {
        const int k = lane + p * 64;
        if (k < c) {
            const int j = idx[(size_t)i * MAXDEG + k];
            const float erj = er_part[j] + er_part[N + j] + er_part[2 * N + j] +
                              er_part[3 * N + j];
            const float s = eli + erj;
            const float lr = s > 0.0f ? s : 0.2f * s;
            const float w = __expf(lr);
            jv[p] = j;
            wv[p] = w;
            wsum += w;
        }
    }
#pragma unroll
    for (int off = 32; off > 0; off >>= 1) wsum += __shfl_down(wsum, off, 64);
    const float denom = fmaxf(__shfl(wsum, 0, 64), 1e-12f);

    float4 a0 = {0, 0, 0, 0}, a1 = {0, 0, 0, 0},
           a2 = {0, 0, 0, 0}, a3 = {0, 0, 0, 0};
    const int c0 = min(c, 64);
    int k = 0;
    for (; k + 4 <= c0; k += 4) {
        const int j0 = __shfl(jv[0], k + 0, 64);
        const int j1 = __shfl(jv[0], k + 1, 64);
        const int j2 = __shfl(jv[0], k + 2, 64);
        const int j3 = __shfl(jv[0], k + 3, 64);
        const float w0 = __shfl(wv[0], k + 0, 64);
        const float w1 = __shfl(wv[0], k + 1, 64);
        const float w2 = __shfl(wv[0], k + 2, 64);
        const float w3 = __shfl(wv[0], k + 3, 64);
        const halfx4 v0 = xh[(size_t)j0 * (D / 4) + lane];
        const halfx4 v1 = xh[(size_t)j1 * (D / 4) + lane];
        const halfx4 v2 = xh[(size_t)j2 * (D / 4) + lane];
        const halfx4 v3 = xh[(size_t)j3 * (D / 4) + lane];
        a0.x = fmaf(w0, (float)v0.x, a0.x); a0.y = fmaf(w0, (float)v0.y, a0.y);
        a0.z = fmaf(w0, (float)v0.z, a0.z); a0.w = fmaf(w0, (float)v0.w, a0.w);
        a1.x = fmaf(w1, (float)v1.x, a1.x); a1.y = fmaf(w1, (float)v1.y, a1.y);
        a1.z = fmaf(w1, (float)v1.z, a1.z); a1.w = fmaf(w1, (float)v1.w, a1.w);
        a2.x = fmaf(w2, (float)v2.x, a2.x); a2.y = fmaf(w2, (float)v2.y, a2.y);
        a2.z = fmaf(w2, (float)v2.z, a2.z); a2.w = fmaf(w2, (float)v2.w, a2.w);
        a3.x = fmaf(w3, (float)v3.x, a3.x); a3.y = fmaf(w3, (float)v3.y, a3.y);
        a3.z = fmaf(w3, (float)v3.z, a3.z); a3.w = fmaf(w3, (float)v3.w, a3.w);
    }
    for (; k < c0; ++k) {
        const int j = __shfl(jv[0], k, 64);
        const float w = __shfl(wv[0], k, 64);
        const halfx4 v = xh[(size_t)j * (D / 4) + lane];
        a0.x = fmaf(w, (float)v.x, a0.x); a0.y = fmaf(w, (float)v.y, a0.y);
        a0.z = fmaf(w, (float)v.z, a0.z); a0.w = fmaf(w, (float)v.w, a0.w);
    }
    for (k = 64; k < c; ++k) {  // ultra-rare (deg > 64)
        const int j = __shfl(jv[1], k - 64, 64);
        const float w = __shfl(wv[1], k - 64, 64);
        const halfx4 v = xh[(size_t)j * (D / 4) + lane];
        a0.x = fmaf(w, (float)v.x, a0.x); a0.y = fmaf(w, (float)v.y, a0.y);
        a0.z = fmaf(w, (float)v.z, a0.z); a0.w = fmaf(w, (float)v.w, a0.w);
    }

    const float inv = 1.0f / denom;
    const float4 bv = *(const float4*)&bias[lane * 4];
    float4 o;
    o.x = (a0.x + a1.x + a2.x + a3.x) * inv + bv.x;
    o.y = (a0.y + a1.y + a2.y + a3.y) * inv + bv.y;
    o.z = (a0.z + a1.z + a2.z + a3.z) * inv + bv.z;
    o.w = (a0.w + a1.w + a2.w + a3.w) * inv + bv.w;
    *(float4*)&out[(size_t)i * D + lane * 4] = o;
}

// ---------------------------------------------------------------------------
extern "C" void kernel_launch(void* const* d_in, const int* in_sizes, int n_in,
                              void* d_out, int out_size, void* d_ws, size_t ws_size,
                              hipStream_t stream) {
    const float* h = (const float*)d_in[0];
    const float* adj = (const float*)d_in[1];
    const float* weight = (const float*)d_in[2];
    const float* a_l = (const float*)d_in[3];
    const float* a_r = (const float*)d_in[4];
    const float* bias = (const float*)d_in[5];
    float* out = (float*)d_out;

    // ws: el_part [4N] | er_part [4N] | cnt [N u32] | idx [N*MAXDEG int] | xh [N*D f16]
    float* el_part = (float*)d_ws;
    float* er_part = el_part + 4 * N;
    unsigned* cnt = (unsigned*)(er_part + 4 * N);
    int* idx = (int*)(cnt + N);
    halfx4* xh = (halfx4*)(idx + (size_t)N * MAXDEG);

    gemm_scan<<<GEMM_BLOCKS + SCAN_BLOCKS, 256, 0, stream>>>(
        h, weight, xh, a_l, a_r, el_part, er_part, adj, cnt, idx);

    gat_out<<<N / 4, 256, 0, stream>>>(cnt, idx, xh, el_part, er_part, bias, out);
}